// Round 8
// baseline (694.860 us; speedup 1.0000x reference)
//
#include <hip/hip_runtime.h>
#include <hip/hip_fp16.h>
#include <math.h>

#define NPTS 2048
#define NB 2
#define NC 128
#define NH 128
#define INV_TEMP 10.0f
#define NITERS 20
#define EPSF 1e-8f
#define NEGINF -3.0e38f

static __device__ __forceinline__ void lse_merge(float& m, float& s, float m2, float s2){
  float M = fmaxf(m, m2);
  s = s * __expf(m - M) + s2 * __expf(m2 - M);
  m = M;
}

// unpack 16B (8 halfs) -> 8 floats
static __device__ __forceinline__ void unpack8(uint4 raw, float* x){
  float2 f;
  f = __half22float2(*(__half2*)&raw.x); x[0]=f.x; x[1]=f.y;
  f = __half22float2(*(((__half2*)&raw.x)+1)); x[2]=f.x; x[3]=f.y;
  f = __half22float2(*(__half2*)&raw.z); x[4]=f.x; x[5]=f.y;
  f = __half22float2(*(((__half2*)&raw.z)+1)); x[6]=f.x; x[7]=f.y;
}

// exact pairwise max tree + 4-way partial exp sums, then wave butterfly
static __device__ __forceinline__ float reduce32_lse(float* x){
  float mt[16];
  #pragma unroll
  for (int i = 0; i < 16; ++i) mt[i] = fmaxf(x[i], x[i + 16]);
  #pragma unroll
  for (int st = 8; st >= 1; st >>= 1)
    #pragma unroll
    for (int i = 0; i < 8; ++i) if (i < st) mt[i] = fmaxf(mt[i], mt[i + st]);
  float m = mt[0];
  float s0 = 0.f, s1 = 0.f, s2 = 0.f, s3 = 0.f;
  #pragma unroll
  for (int i = 0; i < 32; i += 4){
    s0 += __expf(x[i]     - m);
    s1 += __expf(x[i + 1] - m);
    s2 += __expf(x[i + 2] - m);
    s3 += __expf(x[i + 3] - m);
  }
  float s = (s0 + s1) + (s2 + s3);
  #pragma unroll
  for (int d = 1; d < 64; d <<= 1){
    float m2 = __shfl_xor(m, d);
    float sx = __shfl_xor(s, d);
    lse_merge(m, s, m2, sx);
  }
  return m + __logf(s);
}

// ---------------- dustbin head ----------------
__global__ __launch_bounds__(128) void dust_kernel(
    const float* __restrict__ fd, const float* __restrict__ fs,
    const float* __restrict__ W1, const float* __restrict__ b1,
    const float* __restrict__ W2, const float* __restrict__ b2,
    float* __restrict__ dust_d, float* __restrict__ dust_s){
  const int chunk = blockIdx.x, b = blockIdx.y, view = blockIdx.z;
  const float* x = (view == 0 ? fd : fs) + (size_t)b * NC * NPTS;
  float* out = (view == 0 ? dust_d : dust_s) + (size_t)b * NPTS;
  const int n0 = chunk * 16;
  __shared__ float xs[NC][17];
  __shared__ float red[NH][17];
  const int j = threadIdx.x;
  #pragma unroll
  for (int p = 0; p < 16; ++p) xs[j][p] = x[(size_t)j * NPTS + n0 + p];
  __syncthreads();
  float acc[16];
  float bb = b1[j];
  #pragma unroll
  for (int p = 0; p < 16; ++p) acc[p] = bb;
  for (int c = 0; c < NC; ++c){
    float w = W1[j * NC + c];
    #pragma unroll
    for (int p = 0; p < 16; ++p) acc[p] = fmaf(w, xs[c][p], acc[p]);
  }
  float w2 = W2[j];
  #pragma unroll
  for (int p = 0; p < 16; ++p) red[j][p] = w2 * fmaxf(acc[p], 0.0f);
  __syncthreads();
  for (int s = NH / 2; s >= 1; s >>= 1){
    if (j < s){
      #pragma unroll
      for (int p = 0; p < 16; ++p) red[j][p] += red[j + s][p];
    }
    __syncthreads();
  }
  if (j < 16) out[n0 + j] = red[0][j] + b2[0];
}

// ---------------- S = feat_d^T feat_s / TEMP (fp16 only, no transposed copy) ----------------
#define GP 68
#define KC 64
__global__ __launch_bounds__(256) void gemm_kernel(
    const float* __restrict__ fd, const float* __restrict__ fs,
    __half* __restrict__ S){
  const int cb = blockIdx.x, rb = blockIdx.y, b = blockIdx.z;
  const float* A = fd + (size_t)b * NC * NPTS;
  const float* Bm = fs + (size_t)b * NC * NPTS;
  __shared__ float Als[KC * GP];
  __shared__ float Bls[KC * GP];
  const int tid = threadIdx.x;
  const int tx = tid & 15, ty = tid >> 4;
  float acc[4][4] = {};
  for (int kc = 0; kc < NC; kc += KC){
    for (int idx = tid; idx < KC * 64; idx += 256){
      int ch = idx >> 6, i = idx & 63;
      Als[ch * GP + i] = A[(size_t)(kc + ch) * NPTS + rb * 64 + i];
      Bls[ch * GP + i] = Bm[(size_t)(kc + ch) * NPTS + cb * 64 + i];
    }
    __syncthreads();
    for (int c = 0; c < KC; ++c){
      float4 a4 = *(const float4*)&Als[c * GP + ty * 4];
      float4 b4 = *(const float4*)&Bls[c * GP + tx * 4];
      float av[4] = {a4.x, a4.y, a4.z, a4.w};
      float bv[4] = {b4.x, b4.y, b4.z, b4.w};
      #pragma unroll
      for (int i = 0; i < 4; ++i)
        #pragma unroll
        for (int jj = 0; jj < 4; ++jj)
          acc[i][jj] = fmaf(av[i], bv[jj], acc[i][jj]);
    }
    __syncthreads();
  }
  __half* Sb = S + (size_t)b * NPTS * NPTS;
  const int r0 = rb * 64 + ty * 4, c0 = cb * 64 + tx * 4;
  #pragma unroll
  for (int i = 0; i < 4; ++i){
    __half2 p[2];
    p[0] = __float22half2_rn(make_float2(acc[i][0]*INV_TEMP, acc[i][1]*INV_TEMP));
    p[1] = __float22half2_rn(make_float2(acc[i][2]*INV_TEMP, acc[i][3]*INV_TEMP));
    *(uint2*)&Sb[(size_t)(r0 + i) * NPTS + c0] = *(uint2*)p;
  }
}

// ---------------- Sinkhorn half-step, single matrix S, two block types ----------------
// mode 0: row-blocks: u_ds[r] = -lse_j(S[r,j] + v_ds[j]); slot N:   u_ds[N] = -lse_j(dust_d[j]+v_ds[j])
//                                                          slot N+1: u_sd[N] = -lse_i(dust_s[i]+v_sd[i])
//         col-blocks: u_sd[j] = -lse_i(S[i,j] + v_sd[i])
// mode 1: row-blocks: v_sd[i] = -lse( lse_j(S[i,j] + u_sd[j]), dust_s[i] + u_sd[N] )
//         col-blocks: v_ds[j] = -lse( lse_i(S[i,j] + u_ds[i]), dust_d[j] + u_ds[N] )
// Grid is flattened 1-D: first 64 blocks = col-type (2 batches x 32 stripes, dispatched
// first: they carry 8x the bytes of a row-block), then 514 row-type blocks.
#define NCOLBLK (NB * 32)
#define NROWBLK (NB * 257)
__global__ __launch_bounds__(512, 4) void phase_kernel(
    const __half* __restrict__ S,
    const float* __restrict__ dust_d, const float* __restrict__ dust_s,
    float* __restrict__ u_ds, float* __restrict__ u_sd,
    float* __restrict__ v_ds, float* __restrict__ v_sd,
    const int mode){
  const int tid = threadIdx.x;

  if (blockIdx.x < NCOLBLK){
    // ================= column-stripe block: 64 columns, full 2048 rows =================
    const int b  = blockIdx.x >> 5;
    const int j0 = (blockIdx.x & 31) * 64;
    const __half* Sb = S + (size_t)b * NPTS * NPTS;
    __shared__ float lds_off[NPTS];
    __shared__ float mbuf[8 * 64];
    __shared__ float maxfin[64];
    __shared__ float sbuf[8 * 64];
    {
      const float* roff = (mode == 0 ? v_sd + b * NPTS : u_ds + b * (NPTS + 1));
      *(float4*)&lds_off[tid * 4] = *(const float4*)&roff[tid * 4];
    }
    __syncthreads();

    const int ss = tid & 7;        // column octet: cols j0 + ss*8 .. +8
    const int g  = tid >> 3;       // row group 0..63
    const int w  = tid >> 6, lane = tid & 63;
    const size_t base = (size_t)j0 + (size_t)ss * 8;

    // ---- pass 1: per-column max (VALU only) ----
    float m[8];
    #pragma unroll
    for (int i = 0; i < 8; ++i) m[i] = NEGINF;
    for (int rnd = 0; rnd < 32; ++rnd){
      const int r = rnd * 64 + g;
      uint4 raw = *(const uint4*)&Sb[(size_t)r * NPTS + base];
      float off = lds_off[r];
      float xv[8];
      unpack8(raw, xv);
      #pragma unroll
      for (int i = 0; i < 8; ++i) m[i] = fmaxf(m[i], xv[i] + off);
    }
    #pragma unroll
    for (int d = 8; d < 64; d <<= 1)
      #pragma unroll
      for (int i = 0; i < 8; ++i) m[i] = fmaxf(m[i], __shfl_xor(m[i], d));
    if (lane < 8){
      #pragma unroll
      for (int i = 0; i < 8; ++i) mbuf[w * 64 + lane * 8 + i] = m[i];
    }
    __syncthreads();
    if (tid < 64){
      float mf = mbuf[tid];
      #pragma unroll
      for (int ww = 1; ww < 8; ++ww) mf = fmaxf(mf, mbuf[ww * 64 + tid]);
      maxfin[tid] = mf;
    }
    __syncthreads();

    // ---- pass 2: exp-sum against the exact max (stripe is L2-hot) ----
    float ref[8], s[8];
    #pragma unroll
    for (int i = 0; i < 8; ++i){ ref[i] = maxfin[ss * 8 + i]; s[i] = 0.f; }
    for (int rnd = 0; rnd < 32; ++rnd){
      const int r = rnd * 64 + g;
      uint4 raw = *(const uint4*)&Sb[(size_t)r * NPTS + base];
      float off = lds_off[r];
      float xv[8];
      unpack8(raw, xv);
      #pragma unroll
      for (int i = 0; i < 8; ++i) s[i] += __expf(xv[i] + off - ref[i]);
    }
    #pragma unroll
    for (int d = 8; d < 64; d <<= 1)
      #pragma unroll
      for (int i = 0; i < 8; ++i) s[i] += __shfl_xor(s[i], d);
    if (lane < 8){
      #pragma unroll
      for (int i = 0; i < 8; ++i) sbuf[w * 64 + lane * 8 + i] = s[i];
    }
    __syncthreads();
    if (tid < 64){
      float sf = sbuf[tid];
      #pragma unroll
      for (int ww = 1; ww < 8; ++ww) sf += sbuf[ww * 64 + tid];
      float lse = maxfin[tid] + __logf(sf);
      const int j = j0 + tid;
      if (mode == 0){
        u_sd[b * (NPTS + 1) + j] = -lse;
      } else {
        float e = dust_d[b * NPTS + j] + u_ds[b * (NPTS + 1) + NPTS];
        float M2 = fmaxf(lse, e);
        lse = M2 + __logf(__expf(lse - M2) + __expf(e - M2));
        v_ds[b * NPTS + j] = -lse;
      }
    }
    return;
  }

  // ================= row block: 8 rows =================
  const int id = blockIdx.x - NCOLBLK;
  const int b = id & 1;
  const int rbx = id >> 1;
  const int w = tid >> 6, lane = tid & 63;
  const int r = rbx * 8 + w;

  __shared__ float lds_off[NPTS];
  {
    const float* off = (mode == 0 ? v_ds + b * NPTS : u_sd + b * (NPTS + 1));
    *(float4*)&lds_off[tid * 4] = *(const float4*)&off[tid * 4];
  }
  __syncthreads();

  if (mode == 0){
    if (r < NPTS){
      const __half* row = S + ((size_t)b * NPTS + r) * NPTS;
      float x[32];
      #pragma unroll
      for (int k2 = 0; k2 < 4; ++k2){
        const int c = (k2 * 64 + lane) * 8;
        uint4 raw = *(const uint4*)&row[c];
        float xr[8];
        unpack8(raw, xr);
        float4 o0 = *(const float4*)&lds_off[c];
        float4 o1 = *(const float4*)&lds_off[c + 4];
        x[k2*8+0]=xr[0]+o0.x; x[k2*8+1]=xr[1]+o0.y; x[k2*8+2]=xr[2]+o0.z; x[k2*8+3]=xr[3]+o0.w;
        x[k2*8+4]=xr[4]+o1.x; x[k2*8+5]=xr[5]+o1.y; x[k2*8+6]=xr[6]+o1.z; x[k2*8+7]=xr[7]+o1.w;
      }
      float lse = reduce32_lse(x);
      if (lane == 0) u_ds[b * (NPTS + 1) + r] = -lse;
    } else if (r == NPTS || r == NPTS + 1){
      // dust rows: r==N -> u_ds[N] over dust_d + v_ds (LDS); r==N+1 -> u_sd[N] over dust_s + v_sd (global)
      const float* drow = (r == NPTS ? dust_d : dust_s) + b * NPTS;
      const float* offg = v_sd + b * NPTS;  // only used for r==N+1
      float x[32];
      #pragma unroll
      for (int k = 0; k < 8; ++k){
        const int c = (k * 64 + lane) * 4;
        float4 rv = *(const float4*)&drow[c];
        float4 o = (r == NPTS) ? *(const float4*)&lds_off[c] : *(const float4*)&offg[c];
        x[k*4+0]=rv.x+o.x; x[k*4+1]=rv.y+o.y; x[k*4+2]=rv.z+o.z; x[k*4+3]=rv.w+o.w;
      }
      float lse = reduce32_lse(x);
      if (lane == 0){
        if (r == NPTS) u_ds[b * (NPTS + 1) + NPTS] = -lse;
        else           u_sd[b * (NPTS + 1) + NPTS] = -lse;
      }
    }
  } else {
    if (r < NPTS){
      const __half* row = S + ((size_t)b * NPTS + r) * NPTS;
      float x[32];
      #pragma unroll
      for (int k2 = 0; k2 < 4; ++k2){
        const int c = (k2 * 64 + lane) * 8;
        uint4 raw = *(const uint4*)&row[c];
        float xr[8];
        unpack8(raw, xr);
        float4 o0 = *(const float4*)&lds_off[c];
        float4 o1 = *(const float4*)&lds_off[c + 4];
        x[k2*8+0]=xr[0]+o0.x; x[k2*8+1]=xr[1]+o0.y; x[k2*8+2]=xr[2]+o0.z; x[k2*8+3]=xr[3]+o0.w;
        x[k2*8+4]=xr[4]+o1.x; x[k2*8+5]=xr[5]+o1.y; x[k2*8+6]=xr[6]+o1.z; x[k2*8+7]=xr[7]+o1.w;
      }
      float lse = reduce32_lse(x);
      if (lane == 0){
        float e = dust_s[b * NPTS + r] + u_sd[b * (NPTS + 1) + NPTS];
        float M2 = fmaxf(lse, e);
        lse = M2 + __logf(__expf(lse - M2) + __expf(e - M2));
        v_sd[b * NPTS + r] = -lse;
      }
    }
  }
}

// ---------------- final losses: 8 rows/block; entropy via t*y (log skipped; eps error < 1e-3) ----------------
__global__ __launch_bounds__(512, 4) void loss_kernel(
    const __half* __restrict__ S,
    const float* __restrict__ u_ds, const float* __restrict__ u_sd,
    const float* __restrict__ v_ds, const float* __restrict__ v_sd,
    float* __restrict__ part){
  const int b = blockIdx.y;
  const int w = threadIdx.x >> 6, lane = threadIdx.x & 63;
  const int r = blockIdx.x * 8 + w;

  __shared__ float lds_vds[NPTS];
  __shared__ float lds_usd[NPTS];
  *(float4*)&lds_vds[threadIdx.x * 4] = *(const float4*)&v_ds[b * NPTS + threadIdx.x * 4];
  *(float4*)&lds_usd[threadIdx.x * 4] = *(const float4*)&u_sd[b * (NPTS + 1) + threadIdx.x * 4];
  __syncthreads();

  const __half* row = S + ((size_t)b * NPTS + r) * NPTS;
  const float uds = u_ds[b * (NPTS + 1) + r];
  const float vsd = v_sd[b * NPTS + r];
  float sd = 0.f, e1 = 0.f, e2 = 0.f;
  #pragma unroll
  for (int k2 = 0; k2 < 4; ++k2){
    const int c = (k2 * 64 + lane) * 8;
    uint4 raw = *(const uint4*)&row[c];
    float sv[8];
    unpack8(raw, sv);
    float4 a0 = *(const float4*)&lds_vds[c];
    float4 a1 = *(const float4*)&lds_vds[c + 4];
    float4 q0 = *(const float4*)&lds_usd[c];
    float4 q1 = *(const float4*)&lds_usd[c + 4];
    float av[8] = {a0.x,a0.y,a0.z,a0.w,a1.x,a1.y,a1.z,a1.w};
    float qv[8] = {q0.x,q0.y,q0.z,q0.w,q1.x,q1.y,q1.z,q1.w};
    #pragma unroll
    for (int i = 0; i < 8; ++i){
      float y1 = sv[i] + uds + av[i];
      float y2 = sv[i] + qv[i] + vsd;
      float t1 = __expf(y1);   // T_ds[r][c]
      float t2 = __expf(y2);   // T_sd^T[r][c]
      float d = t1 - t2;
      sd += d * d;
      e1 += t1 * y1;           // ~= t1*log(t1+eps)
      e2 += t2 * y2;
    }
  }
  #pragma unroll
  for (int d = 1; d < 64; d <<= 1){
    sd += __shfl_xor(sd, d);
    e1 += __shfl_xor(e1, d);
    e2 += __shfl_xor(e2, d);
  }
  if (lane == 0){
    float* p = part + ((size_t)b * NPTS + r) * 4;
    p[0] = sd; p[1] = e1; p[2] = e2;
  }
}

__global__ __launch_bounds__(256) void final_kernel(const float* __restrict__ part, float* __restrict__ out){
  const int tid = threadIdx.x;
  float s0 = 0.f, s1 = 0.f, s2 = 0.f;
  for (int i = tid; i < NB * NPTS; i += 256){
    s0 += part[(size_t)i * 4 + 0];
    s1 += part[(size_t)i * 4 + 1];
    s2 += part[(size_t)i * 4 + 2];
  }
  #pragma unroll
  for (int d = 1; d < 64; d <<= 1){
    s0 += __shfl_xor(s0, d);
    s1 += __shfl_xor(s1, d);
    s2 += __shfl_xor(s2, d);
  }
  __shared__ float rs[4][3];
  const int w = tid >> 6;
  if ((tid & 63) == 0){ rs[w][0] = s0; rs[w][1] = s1; rs[w][2] = s2; }
  __syncthreads();
  if (tid == 0){
    float a0 = rs[0][0] + rs[1][0] + rs[2][0] + rs[3][0];
    float a1 = rs[0][1] + rs[1][1] + rs[2][1] + rs[3][1];
    float a2 = rs[0][2] + rs[1][2] + rs[2][2] + rs[3][2];
    float lc = a0 / (float)((size_t)NB * NPTS * NPTS);
    float le = -0.5f * (a1 + a2) / (float)NB;
    out[0] = lc + 0.01f * le;
  }
}

extern "C" void kernel_launch(void* const* d_in, const int* in_sizes, int n_in,
                              void* d_out, int out_size, void* d_ws, size_t ws_size,
                              hipStream_t stream){
  const float* fd = (const float*)d_in[0];
  const float* fs = (const float*)d_in[1];
  const float* W1 = (const float*)d_in[2];
  const float* b1 = (const float*)d_in[3];
  const float* W2 = (const float*)d_in[4];
  const float* b2 = (const float*)d_in[5];
  char* ws = (char*)d_ws;
  __half* S = (__half*)ws;                                          // NB*NPTS*NPTS fp16
  float* fws = (float*)(ws + sizeof(__half) * (size_t)NB * NPTS * NPTS);
  float* dust_d = fws;
  float* dust_s = dust_d + (size_t)NB * NPTS;
  float* u_ds   = dust_s + (size_t)NB * NPTS;
  float* u_sd   = u_ds + (size_t)NB * (NPTS + 1);
  float* v_ds   = u_sd + (size_t)NB * (NPTS + 1);
  float* v_sd   = v_ds + (size_t)NB * NPTS;   // adjacent to v_ds (zero-init together)
  float* part   = v_sd + (size_t)NB * NPTS;

  hipMemsetAsync(v_ds, 0, sizeof(float) * (size_t)NB * NPTS * 2, stream);

  dust_kernel<<<dim3(NPTS / 16, NB, 2), 128, 0, stream>>>(fd, fs, W1, b1, W2, b2, dust_d, dust_s);
  gemm_kernel<<<dim3(NPTS / 64, NPTS / 64, NB), 256, 0, stream>>>(fd, fs, S);
  for (int it = 0; it < NITERS; ++it){
    phase_kernel<<<NCOLBLK + NROWBLK, 512, 0, stream>>>(S, dust_d, dust_s, u_ds, u_sd, v_ds, v_sd, 0);
    phase_kernel<<<NCOLBLK + NROWBLK, 512, 0, stream>>>(S, dust_d, dust_s, u_ds, u_sd, v_ds, v_sd, 1);
  }
  loss_kernel<<<dim3(NPTS / 8, NB), 512, 0, stream>>>(S, u_ds, u_sd, v_ds, v_sd, part);
  final_kernel<<<1, 256, 0, stream>>>(part, (float*)d_out);
}

// Round 9
// 357.603 us; speedup vs baseline: 1.9431x; 1.9431x over previous
//
#include <hip/hip_runtime.h>
#include <hip/hip_fp16.h>
#include <math.h>

#define NPTS 2048
#define NB 2
#define NC 128
#define NH 128
#define INV_TEMP 10.0f
#define NITERS 20
#define EPSF 1e-8f

static __device__ __forceinline__ void lse_merge(float& m, float& s, float m2, float s2){
  float M = fmaxf(m, m2);
  s = s * __expf(m - M) + s2 * __expf(m2 - M);
  m = M;
}

// unpack 16B (8 halfs) -> 8 floats
static __device__ __forceinline__ void unpack8(uint4 raw, float* x){
  float2 f;
  f = __half22float2(*(__half2*)&raw.x); x[0]=f.x; x[1]=f.y;
  f = __half22float2(*(((__half2*)&raw.x)+1)); x[2]=f.x; x[3]=f.y;
  f = __half22float2(*(__half2*)&raw.z); x[4]=f.x; x[5]=f.y;
  f = __half22float2(*(((__half2*)&raw.z)+1)); x[6]=f.x; x[7]=f.y;
}

// exact pairwise max tree + 4-way partial exp sums, then wave butterfly
static __device__ __forceinline__ float reduce32_lse(float* x){
  float mt[16];
  #pragma unroll
  for (int i = 0; i < 16; ++i) mt[i] = fmaxf(x[i], x[i + 16]);
  #pragma unroll
  for (int st = 8; st >= 1; st >>= 1)
    #pragma unroll
    for (int i = 0; i < 8; ++i) if (i < st) mt[i] = fmaxf(mt[i], mt[i + st]);
  float m = mt[0];
  float s0 = 0.f, s1 = 0.f, s2 = 0.f, s3 = 0.f;
  #pragma unroll
  for (int i = 0; i < 32; i += 4){
    s0 += __expf(x[i]     - m);
    s1 += __expf(x[i + 1] - m);
    s2 += __expf(x[i + 2] - m);
    s3 += __expf(x[i + 3] - m);
  }
  float s = (s0 + s1) + (s2 + s3);
  #pragma unroll
  for (int d = 1; d < 64; d <<= 1){
    float m2 = __shfl_xor(m, d);
    float sx = __shfl_xor(s, d);
    lse_merge(m, s, m2, sx);
  }
  return m + __logf(s);
}

// ---------------- dustbin head ----------------
__global__ __launch_bounds__(128) void dust_kernel(
    const float* __restrict__ fd, const float* __restrict__ fs,
    const float* __restrict__ W1, const float* __restrict__ b1,
    const float* __restrict__ W2, const float* __restrict__ b2,
    float* __restrict__ dust_d, float* __restrict__ dust_s){
  const int chunk = blockIdx.x, b = blockIdx.y, view = blockIdx.z;
  const float* x = (view == 0 ? fd : fs) + (size_t)b * NC * NPTS;
  float* out = (view == 0 ? dust_d : dust_s) + (size_t)b * NPTS;
  const int n0 = chunk * 16;
  __shared__ float xs[NC][17];
  __shared__ float red[NH][17];
  const int j = threadIdx.x;
  #pragma unroll
  for (int p = 0; p < 16; ++p) xs[j][p] = x[(size_t)j * NPTS + n0 + p];
  __syncthreads();
  float acc[16];
  float bb = b1[j];
  #pragma unroll
  for (int p = 0; p < 16; ++p) acc[p] = bb;
  for (int c = 0; c < NC; ++c){
    float w = W1[j * NC + c];
    #pragma unroll
    for (int p = 0; p < 16; ++p) acc[p] = fmaf(w, xs[c][p], acc[p]);
  }
  float w2 = W2[j];
  #pragma unroll
  for (int p = 0; p < 16; ++p) red[j][p] = w2 * fmaxf(acc[p], 0.0f);
  __syncthreads();
  for (int s = NH / 2; s >= 1; s >>= 1){
    if (j < s){
      #pragma unroll
      for (int p = 0; p < 16; ++p) red[j][p] += red[j + s][p];
    }
    __syncthreads();
  }
  if (j < 16) out[n0 + j] = red[0][j] + b2[0];
}

// ---------------- S = feat_d^T feat_s / TEMP (fp16) + ST via LDS-transposed
//                  coalesced writes; K-chunked staging ----------------
#define GP 68
#define KC 64
#define TP 68   // half-elements stride of transpose tile (136B: 8B-aligned rows)
__global__ __launch_bounds__(256) void gemm_kernel(
    const float* __restrict__ fd, const float* __restrict__ fs,
    __half* __restrict__ S, __half* __restrict__ ST){
  const int cb = blockIdx.x, rb = blockIdx.y, b = blockIdx.z;
  const float* A = fd + (size_t)b * NC * NPTS;
  const float* Bm = fs + (size_t)b * NC * NPTS;
  __shared__ float Als[KC * GP];
  __shared__ float Bls[KC * GP];
  const int tid = threadIdx.x;
  const int tx = tid & 15, ty = tid >> 4;
  float acc[4][4] = {};
  for (int kc = 0; kc < NC; kc += KC){
    for (int idx = tid; idx < KC * 64; idx += 256){
      int ch = idx >> 6, i = idx & 63;
      Als[ch * GP + i] = A[(size_t)(kc + ch) * NPTS + rb * 64 + i];
      Bls[ch * GP + i] = Bm[(size_t)(kc + ch) * NPTS + cb * 64 + i];
    }
    __syncthreads();
    for (int c = 0; c < KC; ++c){
      float4 a4 = *(const float4*)&Als[c * GP + ty * 4];
      float4 b4 = *(const float4*)&Bls[c * GP + tx * 4];
      float av[4] = {a4.x, a4.y, a4.z, a4.w};
      float bv[4] = {b4.x, b4.y, b4.z, b4.w};
      #pragma unroll
      for (int i = 0; i < 4; ++i)
        #pragma unroll
        for (int jj = 0; jj < 4; ++jj)
          acc[i][jj] = fmaf(av[i], bv[jj], acc[i][jj]);
    }
    __syncthreads();
  }
  __half* Sb = S + (size_t)b * NPTS * NPTS;
  __half* STb = ST + (size_t)b * NPTS * NPTS;
  const int r0 = rb * 64 + ty * 4, c0 = cb * 64 + tx * 4;
  // S write: coalesced 128B chunks per (wave, i)
  #pragma unroll
  for (int i = 0; i < 4; ++i){
    __half2 p[2];
    p[0] = __float22half2_rn(make_float2(acc[i][0]*INV_TEMP, acc[i][1]*INV_TEMP));
    p[1] = __float22half2_rn(make_float2(acc[i][2]*INV_TEMP, acc[i][3]*INV_TEMP));
    *(uint2*)&Sb[(size_t)(r0 + i) * NPTS + c0] = *(uint2*)p;
  }
  // ST write: transpose through LDS (overlay Als; compute is done, loop-end sync passed)
  __half* tl = (__half*)Als;   // needs 64*TP*2 = 8704 B << sizeof(Als)
  #pragma unroll
  for (int i = 0; i < 4; ++i)
    #pragma unroll
    for (int jj = 0; jj < 4; ++jj)
      tl[(tx * 4 + jj) * TP + (ty * 4 + i)] = __float2half(acc[i][jj] * INV_TEMP);
  __syncthreads();
  #pragma unroll
  for (int i = 0; i < 4; ++i){
    const int cr = ty * 4 + i;   // row of ST tile = column of S tile
    *(uint2*)&STb[(size_t)(cb * 64 + cr) * NPTS + rb * 64 + tx * 4] =
        *(uint2*)&tl[cr * TP + tx * 4];
  }
}

// ---------------- Sinkhorn half-step: 8 rows/block, offsets in LDS,
//                  uniform grid (256, NB, 2); dust rows folded into block x==0 ----------------
__global__ __launch_bounds__(512, 4) void phase_kernel(
    const __half* __restrict__ S, const __half* __restrict__ ST,
    const float* __restrict__ dust_d, const float* __restrict__ dust_s,
    float* __restrict__ u_ds, float* __restrict__ u_sd,
    float* __restrict__ v_ds, float* __restrict__ v_sd,
    const int mode){
  const int b = blockIdx.y, mat = blockIdx.z;
  const int w = threadIdx.x >> 6, lane = threadIdx.x & 63;
  const int r = blockIdx.x * 8 + w;

  __shared__ float lds_off[NPTS];
  {
    const float* off;
    if (mode == 0) off = (mat == 0 ? v_ds : v_sd) + b * NPTS;
    else           off = (mat == 0 ? u_sd : u_ds) + b * (NPTS + 1);
    *(float4*)&lds_off[threadIdx.x * 4] = *(const float4*)&off[threadIdx.x * 4];
  }
  __syncthreads();

  {
    const __half* row = (mat == 0 ? S : ST) + ((size_t)b * NPTS + r) * NPTS;
    float x[32];
    #pragma unroll
    for (int k2 = 0; k2 < 4; ++k2){
      const int c = (k2 * 64 + lane) * 8;
      uint4 raw = *(const uint4*)&row[c];
      float xr[8];
      unpack8(raw, xr);
      float4 o0 = *(const float4*)&lds_off[c];
      float4 o1 = *(const float4*)&lds_off[c + 4];
      x[k2*8+0]=xr[0]+o0.x; x[k2*8+1]=xr[1]+o0.y; x[k2*8+2]=xr[2]+o0.z; x[k2*8+3]=xr[3]+o0.w;
      x[k2*8+4]=xr[4]+o1.x; x[k2*8+5]=xr[5]+o1.y; x[k2*8+6]=xr[6]+o1.z; x[k2*8+7]=xr[7]+o1.w;
    }
    float lse = reduce32_lse(x);
    if (lane == 0){
      if (mode == 0){
        (mat == 0 ? u_ds : u_sd)[b * (NPTS + 1) + r] = -lse;
      } else {
        float dsc = (mat == 0 ? dust_s : dust_d)[b * NPTS + r];
        float uN  = (mat == 0 ? u_sd : u_ds)[b * (NPTS + 1) + NPTS];
        float e = dsc + uN;
        float M2 = fmaxf(lse, e);
        lse = M2 + __logf(__expf(lse - M2) + __expf(e - M2));
        (mat == 0 ? v_sd : v_ds)[b * NPTS + r] = -lse;
      }
    }
  }

  // dust rows (mode 0 only): u_ds[N] over dust_d+v_ds (mat0), u_sd[N] over dust_s+v_sd (mat1)
  if (mode == 0 && blockIdx.x == 0 && w == 0){
    const float* drow = (mat == 0 ? dust_d : dust_s) + b * NPTS;
    float x[32];
    #pragma unroll
    for (int k = 0; k < 8; ++k){
      const int c = (k * 64 + lane) * 4;
      float4 rv = *(const float4*)&drow[c];
      float4 o  = *(const float4*)&lds_off[c];
      x[k*4+0]=rv.x+o.x; x[k*4+1]=rv.y+o.y; x[k*4+2]=rv.z+o.z; x[k*4+3]=rv.w+o.w;
    }
    float lse = reduce32_lse(x);
    if (lane == 0)
      (mat == 0 ? u_ds : u_sd)[b * (NPTS + 1) + NPTS] = -lse;
  }
}

// ---------------- final losses: 8 rows/block; entropy via t*y (eps error < 5e-4) ----------------
__global__ __launch_bounds__(512, 4) void loss_kernel(
    const __half* __restrict__ S,
    const float* __restrict__ u_ds, const float* __restrict__ u_sd,
    const float* __restrict__ v_ds, const float* __restrict__ v_sd,
    float* __restrict__ part){
  const int b = blockIdx.y;
  const int w = threadIdx.x >> 6, lane = threadIdx.x & 63;
  const int r = blockIdx.x * 8 + w;

  __shared__ float lds_vds[NPTS];
  __shared__ float lds_usd[NPTS];
  *(float4*)&lds_vds[threadIdx.x * 4] = *(const float4*)&v_ds[b * NPTS + threadIdx.x * 4];
  *(float4*)&lds_usd[threadIdx.x * 4] = *(const float4*)&u_sd[b * (NPTS + 1) + threadIdx.x * 4];
  __syncthreads();

  const __half* row = S + ((size_t)b * NPTS + r) * NPTS;
  const float uds = u_ds[b * (NPTS + 1) + r];
  const float vsd = v_sd[b * NPTS + r];
  float sd = 0.f, e1 = 0.f, e2 = 0.f;
  #pragma unroll
  for (int k2 = 0; k2 < 4; ++k2){
    const int c = (k2 * 64 + lane) * 8;
    uint4 raw = *(const uint4*)&row[c];
    float sv[8];
    unpack8(raw, sv);
    float4 a0 = *(const float4*)&lds_vds[c];
    float4 a1 = *(const float4*)&lds_vds[c + 4];
    float4 q0 = *(const float4*)&lds_usd[c];
    float4 q1 = *(const float4*)&lds_usd[c + 4];
    float av[8] = {a0.x,a0.y,a0.z,a0.w,a1.x,a1.y,a1.z,a1.w};
    float qv[8] = {q0.x,q0.y,q0.z,q0.w,q1.x,q1.y,q1.z,q1.w};
    #pragma unroll
    for (int i = 0; i < 8; ++i){
      float y1 = sv[i] + uds + av[i];
      float y2 = sv[i] + qv[i] + vsd;
      float t1 = __expf(y1);   // T_ds[r][c]
      float t2 = __expf(y2);   // T_sd^T[r][c]
      float d = t1 - t2;
      sd += d * d;
      e1 += t1 * y1;           // ~= t1*log(t1+eps)
      e2 += t2 * y2;
    }
  }
  #pragma unroll
  for (int d = 1; d < 64; d <<= 1){
    sd += __shfl_xor(sd, d);
    e1 += __shfl_xor(e1, d);
    e2 += __shfl_xor(e2, d);
  }
  if (lane == 0){
    float* p = part + ((size_t)b * NPTS + r) * 4;
    p[0] = sd; p[1] = e1; p[2] = e2;
  }
}

__global__ __launch_bounds__(256) void final_kernel(const float* __restrict__ part, float* __restrict__ out){
  const int tid = threadIdx.x;
  float s0 = 0.f, s1 = 0.f, s2 = 0.f;
  for (int i = tid; i < NB * NPTS; i += 256){
    s0 += part[(size_t)i * 4 + 0];
    s1 += part[(size_t)i * 4 + 1];
    s2 += part[(size_t)i * 4 + 2];
  }
  #pragma unroll
  for (int d = 1; d < 64; d <<= 1){
    s0 += __shfl_xor(s0, d);
    s1 += __shfl_xor(s1, d);
    s2 += __shfl_xor(s2, d);
  }
  __shared__ float rs[4][3];
  const int w = tid >> 6;
  if ((tid & 63) == 0){ rs[w][0] = s0; rs[w][1] = s1; rs[w][2] = s2; }
  __syncthreads();
  if (tid == 0){
    float a0 = rs[0][0] + rs[1][0] + rs[2][0] + rs[3][0];
    float a1 = rs[0][1] + rs[1][1] + rs[2][1] + rs[3][1];
    float a2 = rs[0][2] + rs[1][2] + rs[2][2] + rs[3][2];
    float lc = a0 / (float)((size_t)NB * NPTS * NPTS);
    float le = -0.5f * (a1 + a2) / (float)NB;
    out[0] = lc + 0.01f * le;
  }
}

extern "C" void kernel_launch(void* const* d_in, const int* in_sizes, int n_in,
                              void* d_out, int out_size, void* d_ws, size_t ws_size,
                              hipStream_t stream){
  const float* fd = (const float*)d_in[0];
  const float* fs = (const float*)d_in[1];
  const float* W1 = (const float*)d_in[2];
  const float* b1 = (const float*)d_in[3];
  const float* W2 = (const float*)d_in[4];
  const float* b2 = (const float*)d_in[5];
  char* ws = (char*)d_ws;
  __half* S  = (__half*)ws;
  __half* ST = S + (size_t)NB * NPTS * NPTS;
  float* fws = (float*)(ws + 2 * sizeof(__half) * (size_t)NB * NPTS * NPTS);
  float* dust_d = fws;
  float* dust_s = dust_d + (size_t)NB * NPTS;
  float* u_ds   = dust_s + (size_t)NB * NPTS;
  float* u_sd   = u_ds + (size_t)NB * (NPTS + 1);
  float* v_ds   = u_sd + (size_t)NB * (NPTS + 1);
  float* v_sd   = v_ds + (size_t)NB * NPTS;   // adjacent to v_ds (zero-init together)
  float* part   = v_sd + (size_t)NB * NPTS;

  hipMemsetAsync(v_ds, 0, sizeof(float) * (size_t)NB * NPTS * 2, stream);

  dust_kernel<<<dim3(NPTS / 16, NB, 2), 128, 0, stream>>>(fd, fs, W1, b1, W2, b2, dust_d, dust_s);
  gemm_kernel<<<dim3(NPTS / 64, NPTS / 64, NB), 256, 0, stream>>>(fd, fs, S, ST);
  const dim3 pgrid(NPTS / 8, NB, 2);   // uniform across modes & launches
  for (int it = 0; it < NITERS; ++it){
    phase_kernel<<<pgrid, 512, 0, stream>>>(S, ST, dust_d, dust_s, u_ds, u_sd, v_ds, v_sd, 0);
    phase_kernel<<<pgrid, 512, 0, stream>>>(S, ST, dust_d, dust_s, u_ds, u_sd, v_ds, v_sd, 1);
  }
  loss_kernel<<<dim3(NPTS / 8, NB), 512, 0, stream>>>(S, u_ds, u_sd, v_ds, v_sd, part);
  final_kernel<<<1, 256, 0, stream>>>(part, (float*)d_out);
}